// Round 2
// baseline (337.169 us; speedup 1.0000x reference)
//
#include <hip/hip_runtime.h>
#include <hip/hip_bf16.h>
#include <math.h>

#define C_   128
#define HW_  4096
#define OC_  100
#define NSTAT_ 32768.0f

typedef __bf16 bf16x8 __attribute__((ext_vector_type(8)));
typedef __bf16 bf16x4 __attribute__((ext_vector_type(4)));
typedef float  f32x4  __attribute__((ext_vector_type(4)));

// ---------------- K1: 1x1 conv via MFMA bf16 -> t1c[b][px][64] bf16 + stats + wprep --------
// grid 512 = b(8) x chunk(64 of 64px); 256 thr = 4 waves, wave = one 16-px m-tile, N=64.
__global__ __launch_bounds__(256, 4) void k_conv1(const float* __restrict__ x,
                                                  const float* __restrict__ w,
                                                  const float* __restrict__ wenc,
                                                  __bf16* __restrict__ t1c,
                                                  float* __restrict__ csum,
                                                  float* __restrict__ csq,
                                                  __bf16* __restrict__ wprep) {
    __shared__ __bf16 xt[64 * 128];   // [px][ic], 256B rows, 16B-block XOR swizzle
    __shared__ __bf16 wt[64 * 128];   // [oc][ic], same swizzle
    __shared__ float sS[64], sQ[64];

    int blk = blockIdx.x;
    int b = blk & 7;
    int chunk = blk >> 3;             // 0..63
    int px0 = chunk * 64;
    int tid = threadIdx.x;
    if (tid < 64) { sS[tid] = 0.f; sQ[tid] = 0.f; }

    // pack enc weights -> wprep[oc 112][k 576], k = tap*64+ic  (blocks 0..62, 1024 each)
    if (blk < 63) {
#pragma unroll
        for (int u = 0; u < 4; ++u) {
            int idx = blk * 1024 + u * 256 + tid;   // < 64512 = 112*576
            int oc = idx / 576, k = idx - oc * 576;
            int tap = k >> 6, ic = k & 63;
            wprep[idx] = (oc < OC_) ? (__bf16)wenc[((size_t)oc * 64 + ic) * 9 + tap]
                                    : (__bf16)0.f;
        }
    }

    // stage comp_w (64 oc x 128 ic fp32) -> wt bf16: 2048 float4 jobs
#pragma unroll
    for (int it = 0; it < 8; ++it) {
        int j = it * 256 + tid;       // 0..2047
        int oc = j >> 5, f = j & 31;
        float4 v = *(const float4*)(w + (size_t)oc * 128 + f * 4);
        int blki = (f >> 1) ^ (oc & 15);
        bf16x4 st;
        st[0] = (__bf16)v.x; st[1] = (__bf16)v.y; st[2] = (__bf16)v.z; st[3] = (__bf16)v.w;
        *(bf16x4*)&wt[oc * 128 + blki * 8 + (f & 1) * 4] = st;
    }
    // stage x tile (64 px x 128 ic) -> xt bf16 (transpose 4x4 in regs), 512 jobs x 16 floats
#pragma unroll
    for (int it = 0; it < 2; ++it) {
        int j = it * 256 + tid;
        int px4 = (j & 15) * 4, icq = j >> 4;   // icq 0..31
        const float* xp = x + ((size_t)b * C_ + icq * 4) * HW_ + px0 + px4;
        float4 v0 = *(const float4*)(xp);
        float4 v1 = *(const float4*)(xp + HW_);
        float4 v2 = *(const float4*)(xp + 2 * HW_);
        float4 v3 = *(const float4*)(xp + 3 * HW_);
        float r0[4] = {v0.x, v0.y, v0.z, v0.w};
        float r1[4] = {v1.x, v1.y, v1.z, v1.w};
        float r2_[4] = {v2.x, v2.y, v2.z, v2.w};
        float r3[4] = {v3.x, v3.y, v3.z, v3.w};
#pragma unroll
        for (int r2 = 0; r2 < 4; ++r2) {
            int px = px4 + r2;
            int blki = (icq >> 1) ^ (px & 15);
            bf16x4 st;
            st[0] = (__bf16)r0[r2]; st[1] = (__bf16)r1[r2];
            st[2] = (__bf16)r2_[r2]; st[3] = (__bf16)r3[r2];
            *(bf16x4*)&xt[px * 128 + blki * 8 + (icq & 1) * 4] = st;
        }
    }
    __syncthreads();

    int lane = tid & 63, wv = tid >> 6;
    int p = lane & 15, q = lane >> 4;

    f32x4 acc[4];
#pragma unroll
    for (int n = 0; n < 4; ++n) acc[n] = (f32x4){0.f, 0.f, 0.f, 0.f};

#pragma unroll
    for (int kk = 0; kk < 4; ++kk) {
        int blki = (kk * 4 + q) ^ p;
        bf16x8 a = *(const bf16x8*)&xt[(wv * 16 + p) * 128 + blki * 8];
#pragma unroll
        for (int n = 0; n < 4; ++n) {
            bf16x8 bb = *(const bf16x8*)&wt[(n * 16 + p) * 128 + blki * 8];
            acc[n] = __builtin_amdgcn_mfma_f32_16x16x32_bf16(a, bb, acc[n], 0, 0, 0);
        }
    }

    // D: col(oc within tile) = p, row(px within tile) = q*4+rg
    __bf16* t1b = t1c + ((size_t)b * HW_ + px0 + wv * 16) * 64;
#pragma unroll
    for (int n = 0; n < 4; ++n) {
        float s = 0.f, qq = 0.f;
#pragma unroll
        for (int rg = 0; rg < 4; ++rg) {
            float v = acc[n][rg];
            t1b[(size_t)(q * 4 + rg) * 64 + n * 16 + p] = (__bf16)v;
            s += v; qq += v * v;
        }
        s += __shfl_down(s, 32, 64);  s += __shfl_down(s, 16, 64);
        qq += __shfl_down(qq, 32, 64); qq += __shfl_down(qq, 16, 64);
        if (lane < 16) {
            atomicAdd(&sS[n * 16 + p], s);
            atomicAdd(&sQ[n * 16 + p], qq);
        }
    }
    __syncthreads();
    if (tid < 64) {
        atomicAdd(&csum[tid], sS[tid]);
        atomicAdd(&csq[tid], sQ[tid]);
    }
}

// ---------------- K2: 3x3 conv MFMA; B-operand through double-buffered LDS ----------------
// grid 512 = b(8) x tile(64 of 8x8 px); 256 thr = 4 waves.
__global__ __launch_bounds__(256, 4) void k_conv3(const __bf16* __restrict__ t1c,
                                                  const __bf16* __restrict__ wprep,
                                                  const float* __restrict__ csum,
                                                  const float* __restrict__ csq,
                                                  const float* __restrict__ cg,
                                                  const float* __restrict__ cb,
                                                  float* __restrict__ t2c,
                                                  float* __restrict__ esum,
                                                  float* __restrict__ esq) {
    __shared__ __bf16 xt[10 * 10 * 72];        // 14400 B
    __shared__ __bf16 bt[2][112 * 32];         // [buf][oc][32k] = 2 x 7168 B
    __shared__ float lsc[64], lsh[64];
    __shared__ float esuml[112], esql[112];

    int blk = blockIdx.x;
    int b = blk & 7;
    int tile = blk >> 3;
    int ty0 = (tile >> 3) * 8, tx0 = (tile & 7) * 8;
    int tid = threadIdx.x;
    if (tid < 112) { esuml[tid] = 0.f; esql[tid] = 0.f; }
    if (tid >= 128 && tid < 192) {
        int c = tid - 128;
        float invN = 1.0f / NSTAT_;
        float m = csum[c] * invN;
        float v = csq[c] * invN - m * m;
        float rs = rsqrtf(v + 1e-5f);
        float sc = cg[c] * rs;
        lsc[c] = sc;
        lsh[c] = cb[c] - m * sc;
    }
    __syncthreads();   // lsc/lsh ready for staging

    // prologue: stage B chunk kk=0 into bt[0]  (448 chunks of 16B)
    {
        int oc = tid >> 2, part = tid & 3;
        *(bf16x8*)&bt[0][oc * 32 + part * 8] =
            *(const bf16x8*)(wprep + (size_t)oc * 576 + part * 8);
        if (tid < 192) {
            int c1 = tid + 256;
            int oc1 = c1 >> 2, p1 = c1 & 3;
            *(bf16x8*)&bt[0][oc1 * 32 + p1 * 8] =
                *(const bf16x8*)(wprep + (size_t)oc1 * 576 + p1 * 8);
        }
    }

    // stage BN+SiLU(t1) 10x10 halo -> xt  (1600 jobs of 4 ic)
    const __bf16* tb = t1c + (size_t)b * HW_ * 64;
#pragma unroll
    for (int it = 0; it < 7; ++it) {
        int idx = it * 256 + tid;
        if (idx < 1600) {
            int pxi = idx >> 4, f4 = idx & 15;
            int yy = pxi / 10, xx = pxi - yy * 10;
            int gy = ty0 + yy - 1, gx = tx0 + xx - 1;
            float o0 = 0.f, o1 = 0.f, o2 = 0.f, o3 = 0.f;
            if (gy >= 0 && gy < 64 && gx >= 0 && gx < 64) {
                bf16x4 v = *(const bf16x4*)(tb + ((size_t)(gy << 6) + gx) * 64 + f4 * 4);
                float4 sc = *(const float4*)(lsc + f4 * 4);
                float4 sh = *(const float4*)(lsh + f4 * 4);
                float u;
                u = fmaf((float)v[0], sc.x, sh.x); o0 = u / (1.f + __expf(-u));
                u = fmaf((float)v[1], sc.y, sh.y); o1 = u / (1.f + __expf(-u));
                u = fmaf((float)v[2], sc.z, sh.z); o2 = u / (1.f + __expf(-u));
                u = fmaf((float)v[3], sc.w, sh.w); o3 = u / (1.f + __expf(-u));
            }
            bf16x4 st;
            st[0] = (__bf16)o0; st[1] = (__bf16)o1; st[2] = (__bf16)o2; st[3] = (__bf16)o3;
            *(bf16x4*)&xt[pxi * 72 + f4 * 4] = st;
        }
    }
    __syncthreads();   // bt[0] + xt ready

    int lane = tid & 63, wv = tid >> 6;
    int p = lane & 15, q = lane >> 4;
    int ya = 2 * wv + (p >> 3), xa = p & 7;
    int soc = tid >> 2, spart = tid & 3;          // staging roles
    int soc1 = (tid + 256) >> 2, spart1 = (tid + 256) & 3;

    f32x4 acc[7];
#pragma unroll
    for (int n = 0; n < 7; ++n) acc[n] = (f32x4){0.f, 0.f, 0.f, 0.f};

#pragma unroll
    for (int kk = 0; kk < 18; ++kk) {
        const int cur = kk & 1;
        // prefetch B chunk kk+1 into regs (coalesced 16B loads, latency overlapped)
        bf16x8 r0, r1;
        if (kk < 17) {
            r0 = *(const bf16x8*)(wprep + (size_t)soc * 576 + (kk + 1) * 32 + spart * 8);
            if (tid < 192)
                r1 = *(const bf16x8*)(wprep + (size_t)soc1 * 576 + (kk + 1) * 32 + spart1 * 8);
        }
        // compute from bt[cur]
        const int tap = kk >> 1, ich = (kk & 1) * 32;
        const int ky = tap / 3, kx = tap - ky * 3;
        bf16x8 a0 = *(const bf16x8*)&xt[((ya + ky) * 10 + xa + kx) * 72 + ich + q * 8];
#pragma unroll
        for (int n = 0; n < 7; ++n) {
            bf16x8 bb = *(const bf16x8*)&bt[cur][(n * 16 + p) * 32 + q * 8];
            acc[n] = __builtin_amdgcn_mfma_f32_16x16x32_bf16(a0, bb, acc[n], 0, 0, 0);
        }
        // write prefetched chunk to the other buffer
        if (kk < 17) {
            *(bf16x8*)&bt[1 - cur][soc * 32 + spart * 8] = r0;
            if (tid < 192)
                *(bf16x8*)&bt[1 - cur][soc1 * 32 + spart1 * 8] = r1;
            __syncthreads();
        }
    }

    float* t2b = t2c + (size_t)b * HW_ * 112;
#pragma unroll
    for (int n = 0; n < 7; ++n) {
        float s = 0.f, qq = 0.f;
#pragma unroll
        for (int rg = 0; rg < 4; ++rg) {
            int mp = q * 4 + rg;
            int y = ty0 + 2 * wv + (mp >> 3), xo = tx0 + (mp & 7);
            float v = acc[n][rg];
            t2b[((size_t)y * 64 + xo) * 112 + n * 16 + p] = v;
            s += v; qq += v * v;
        }
        s += __shfl_down(s, 32, 64);  s += __shfl_down(s, 16, 64);
        qq += __shfl_down(qq, 32, 64); qq += __shfl_down(qq, 16, 64);
        if (lane < 16) {
            atomicAdd(&esuml[n * 16 + lane], s);
            atomicAdd(&esql[n * 16 + lane], qq);
        }
    }
    __syncthreads();
    if (tid < 112) {
        atomicAdd(&esum[tid], esuml[tid]);
        atomicAdd(&esq[tid], esql[tid]);
    }
}

// ---------------- K3: BN2 + softmax + reassembly; subpixel-PAIR per thread ----------------
// Read-sharing kept (each ds_read_b128 feeds 8 FMAs), occupancy restored:
// channels split into 4 quarters (32 ch = 2 double-buffered 16-ch stages per block).
// grid 1024 = b(8) x tile(32: 4tx x 8ty of 16x8 lowres) x cq(4); 4 blocks/CU, 16 waves/CU.
// VGPR target 128 (launch_bounds 256,4): wA/wB 50 + accA/accB 32 + pf 16 + inline addressing.
__global__ __launch_bounds__(256, 4) void k_carafe(const float* __restrict__ x,
                                                   const float* __restrict__ t2c,
                                                   const float* __restrict__ esum,
                                                   const float* __restrict__ esq,
                                                   const float* __restrict__ eg,
                                                   const float* __restrict__ eb,
                                                   float* __restrict__ out) {
    __shared__ float xt[2][240 * 20];  // [buf][halo px 12x20][16 ch pad 20] = 2 x 19200 B
    __shared__ float esc[112], esh[112];

    int blk = blockIdx.x;
    int b = blk & 7;
    int r = blk >> 3;                  // 0..127
    int tile = r & 31;
    int cq = r >> 5;                   // 0..3 channel quarter (32 ch)
    int tx0 = (tile & 3) * 16, ty0 = (tile >> 2) * 8;
    int tid = threadIdx.x;
    if (tid < 112) {
        float invN = 1.0f / NSTAT_;
        float m = esum[tid] * invN;
        float v = esq[tid] * invN - m * m;
        float rs = rsqrtf(v + 1e-5f);
        float sc = (tid < OC_) ? eg[tid] * rs : 0.f;
        esc[tid] = sc;
        esh[tid] = (tid < OC_) ? eb[tid] - m * sc : 0.f;
    }
    __syncthreads();

    int t0 = tid & 1, px = tid >> 1;      // t0 = si (output row within 2x2)
    int pxx = px & 15, py = px >> 4;      // py 0..7
    int iy = ty0 + py, jx = tx0 + pxx;

    // two softmaxes: s = 2*t0 (sj=0) and s = 2*t0+1 (sj=1); weight channel = 4k+s
    float wA[25], wB[25];
    {
        const float* t2p = t2c + ((size_t)((b << 12) + (iy << 6) + jx)) * 112 + 2 * t0;
        int cA = 2 * t0, cB = 2 * t0 + 1;
        float mxA = -1e30f, mxB = -1e30f;
#pragma unroll
        for (int k = 0; k < 25; ++k) {
            float2 v = *(const float2*)(t2p + 4 * k);
            float lA = fmaf(v.x, esc[4 * k + cA], esh[4 * k + cA]);
            float lB = fmaf(v.y, esc[4 * k + cB], esh[4 * k + cB]);
            wA[k] = lA; wB[k] = lB;
            mxA = fmaxf(mxA, lA); mxB = fmaxf(mxB, lB);
        }
        float sA = 0.f, sB = 0.f;
#pragma unroll
        for (int k = 0; k < 25; ++k) {
            float eA = __expf(wA[k] - mxA);
            float eB = __expf(wB[k] - mxB);
            wA[k] = eA; wB[k] = eB;
            sA += eA; sB += eB;
        }
        float iA = 1.f / sA, iB = 1.f / sB;
#pragma unroll
        for (int k = 0; k < 25; ++k) { wA[k] *= iA; wB[k] *= iB; }
    }

    const float* xb = x + (size_t)b * C_ * HW_;
    int i0 = iy * 2 + t0;
    float* op = out + (size_t)b * C_ * 16384 + (size_t)i0 * 128 + jx * 2;

    // prologue: stage channels [cq*32, cq*32+16) into xt[0]
    // 960 jobs (12x20 halo px x 4 c-quads), indices recomputed inline (saves ~20 VGPR)
#pragma unroll
    for (int it = 0; it < 4; ++it) {
        int idx = it * 256 + tid;
        if (idx < 960) {
            int c4 = idx / 240;
            int r2 = idx - c4 * 240;
            int yy = r2 / 20, xx = r2 - yy * 20;
            int gy = ty0 - 2 + yy, gx = tx0 - 2 + xx;
            f32x4 st = {0.f, 0.f, 0.f, 0.f};
            if (gy >= 0 && gy < 64 && gx >= 0 && gx < 64) {
                size_t base = (size_t)(cq * 32 + c4 * 4) * HW_ + (gy << 6) + gx;
                st[0] = xb[base];
                st[1] = xb[base + HW_];
                st[2] = xb[base + 2 * HW_];
                st[3] = xb[base + 3 * HW_];
            }
            *(f32x4*)&xt[0][r2 * 20 + c4 * 4] = st;
        }
    }

#pragma unroll 1
    for (int stage = 0; stage < 2; ++stage) {
        int cur = stage & 1;
        int cbase = cq * 32 + stage * 16;
        // prefetch next stage's 16 channels into regs
        f32x4 pf[4];
        if (stage < 1) {
#pragma unroll
            for (int it = 0; it < 4; ++it) {
                int idx = it * 256 + tid;
                if (idx < 960) {
                    int c4 = idx / 240;
                    int r2 = idx - c4 * 240;
                    int yy = r2 / 20, xx = r2 - yy * 20;
                    int gy = ty0 - 2 + yy, gx = tx0 - 2 + xx;
                    f32x4 st = {0.f, 0.f, 0.f, 0.f};
                    if (gy >= 0 && gy < 64 && gx >= 0 && gx < 64) {
                        size_t base = (size_t)(cbase + 16 + c4 * 4) * HW_ + (gy << 6) + gx;
                        st[0] = xb[base];
                        st[1] = xb[base + HW_];
                        st[2] = xb[base + 2 * HW_];
                        st[3] = xb[base + 3 * HW_];
                    }
                    pf[it] = st;
                }
            }
        }
        __syncthreads();   // xt[cur] ready

        float accA[16], accB[16];
#pragma unroll
        for (int e = 0; e < 16; ++e) { accA[e] = 0.f; accB[e] = 0.f; }
#pragma unroll
        for (int dy = 0; dy < 5; ++dy)
#pragma unroll
            for (int dx = 0; dx < 5; ++dx) {
                int pos = (py + dy) * 20 + pxx + dx;
                float a = wA[dy * 5 + dx], bw = wB[dy * 5 + dx];
#pragma unroll
                for (int c4 = 0; c4 < 4; ++c4) {
                    f32x4 xv = *(const f32x4*)&xt[cur][pos * 20 + c4 * 4];
                    accA[c4 * 4 + 0] = fmaf(a, xv[0], accA[c4 * 4 + 0]);
                    accA[c4 * 4 + 1] = fmaf(a, xv[1], accA[c4 * 4 + 1]);
                    accA[c4 * 4 + 2] = fmaf(a, xv[2], accA[c4 * 4 + 2]);
                    accA[c4 * 4 + 3] = fmaf(a, xv[3], accA[c4 * 4 + 3]);
                    accB[c4 * 4 + 0] = fmaf(bw, xv[0], accB[c4 * 4 + 0]);
                    accB[c4 * 4 + 1] = fmaf(bw, xv[1], accB[c4 * 4 + 1]);
                    accB[c4 * 4 + 2] = fmaf(bw, xv[2], accB[c4 * 4 + 2]);
                    accB[c4 * 4 + 3] = fmaf(bw, xv[3], accB[c4 * 4 + 3]);
                }
            }
        // paired subpixels are adjacent output columns -> 8B vector stores
#pragma unroll
        for (int e = 0; e < 16; ++e) {
            float2 st2;
            st2.x = accA[e]; st2.y = accB[e];
            *(float2*)&op[(size_t)(cbase + e) * 16384] = st2;
        }

        if (stage < 1) {
#pragma unroll
            for (int it = 0; it < 4; ++it) {
                int idx = it * 256 + tid;
                if (idx < 960) {
                    int c4 = idx / 240;
                    int r2 = idx - c4 * 240;
                    *(f32x4*)&xt[1 - cur][r2 * 20 + c4 * 4] = pf[it];
                }
            }
        }
    }
}

extern "C" void kernel_launch(void* const* d_in, const int* in_sizes, int n_in,
                              void* d_out, int out_size, void* d_ws, size_t ws_size,
                              hipStream_t stream) {
    const float* x      = (const float*)d_in[0];
    const float* comp_w = (const float*)d_in[1];
    const float* comp_g = (const float*)d_in[2];
    const float* comp_b = (const float*)d_in[3];
    const float* enc_w  = (const float*)d_in[4];
    const float* enc_g  = (const float*)d_in[5];
    const float* enc_b  = (const float*)d_in[6];
    float* out = (float*)d_out;

    float* ws = (float*)d_ws;
    __bf16* t1c = (__bf16*)ws;             // 8*4096*64 bf16 = 4 MB
    float* t2c  = ws + 1048576;            // 8*4096*112 fp32 = 14.7 MB
    float* st   = ws + 1048576 + 3670016;
    float* csum = st;                      // 64
    float* csq  = st + 64;                 // 64
    float* esum = st + 128;                // 112
    float* esq  = st + 240;                // 112
    __bf16* wprep = (__bf16*)(st + 352);   // 112*576 bf16

    hipMemsetAsync(st, 0, 352 * sizeof(float), stream);
    k_conv1<<<512, 256, 0, stream>>>(x, comp_w, enc_w, t1c, csum, csq, wprep);
    k_conv3<<<512, 256, 0, stream>>>(t1c, wprep, csum, csq, comp_g, comp_b, t2c, esum, esq);
    k_carafe<<<1024, 256, 0, stream>>>(x, t2c, esum, esq, enc_g, enc_b, out);
}

// Round 3
// 176.624 us; speedup vs baseline: 1.9090x; 1.9090x over previous
//
#include <hip/hip_runtime.h>
#include <hip/hip_bf16.h>
#include <math.h>

#define C_   128
#define HW_  4096
#define OC_  100
#define NSTAT_ 32768.0f

typedef __bf16 bf16x8 __attribute__((ext_vector_type(8)));
typedef __bf16 bf16x4 __attribute__((ext_vector_type(4)));
typedef float  f32x4  __attribute__((ext_vector_type(4)));

// ---------------- K1: 1x1 conv via MFMA bf16 -> t1c[b][px][64] bf16 + stats + wprep --------
// grid 512 = b(8) x chunk(64 of 64px); 256 thr = 4 waves, wave = one 16-px m-tile, N=64.
__global__ __launch_bounds__(256, 4) void k_conv1(const float* __restrict__ x,
                                                  const float* __restrict__ w,
                                                  const float* __restrict__ wenc,
                                                  __bf16* __restrict__ t1c,
                                                  float* __restrict__ csum,
                                                  float* __restrict__ csq,
                                                  __bf16* __restrict__ wprep) {
    __shared__ __bf16 xt[64 * 128];   // [px][ic], 256B rows, 16B-block XOR swizzle
    __shared__ __bf16 wt[64 * 128];   // [oc][ic], same swizzle
    __shared__ float sS[64], sQ[64];

    int blk = blockIdx.x;
    int b = blk & 7;
    int chunk = blk >> 3;             // 0..63
    int px0 = chunk * 64;
    int tid = threadIdx.x;
    if (tid < 64) { sS[tid] = 0.f; sQ[tid] = 0.f; }

    // pack enc weights -> wprep[oc 112][k 576], k = tap*64+ic  (blocks 0..62, 1024 each)
    if (blk < 63) {
#pragma unroll
        for (int u = 0; u < 4; ++u) {
            int idx = blk * 1024 + u * 256 + tid;   // < 64512 = 112*576
            int oc = idx / 576, k = idx - oc * 576;
            int tap = k >> 6, ic = k & 63;
            wprep[idx] = (oc < OC_) ? (__bf16)wenc[((size_t)oc * 64 + ic) * 9 + tap]
                                    : (__bf16)0.f;
        }
    }

    // stage comp_w (64 oc x 128 ic fp32) -> wt bf16: 2048 float4 jobs
#pragma unroll
    for (int it = 0; it < 8; ++it) {
        int j = it * 256 + tid;       // 0..2047
        int oc = j >> 5, f = j & 31;
        float4 v = *(const float4*)(w + (size_t)oc * 128 + f * 4);
        int blki = (f >> 1) ^ (oc & 15);
        bf16x4 st;
        st[0] = (__bf16)v.x; st[1] = (__bf16)v.y; st[2] = (__bf16)v.z; st[3] = (__bf16)v.w;
        *(bf16x4*)&wt[oc * 128 + blki * 8 + (f & 1) * 4] = st;
    }
    // stage x tile (64 px x 128 ic) -> xt bf16 (transpose 4x4 in regs), 512 jobs x 16 floats
#pragma unroll
    for (int it = 0; it < 2; ++it) {
        int j = it * 256 + tid;
        int px4 = (j & 15) * 4, icq = j >> 4;   // icq 0..31
        const float* xp = x + ((size_t)b * C_ + icq * 4) * HW_ + px0 + px4;
        float4 v0 = *(const float4*)(xp);
        float4 v1 = *(const float4*)(xp + HW_);
        float4 v2 = *(const float4*)(xp + 2 * HW_);
        float4 v3 = *(const float4*)(xp + 3 * HW_);
        float r0[4] = {v0.x, v0.y, v0.z, v0.w};
        float r1[4] = {v1.x, v1.y, v1.z, v1.w};
        float r2_[4] = {v2.x, v2.y, v2.z, v2.w};
        float r3[4] = {v3.x, v3.y, v3.z, v3.w};
#pragma unroll
        for (int r2 = 0; r2 < 4; ++r2) {
            int px = px4 + r2;
            int blki = (icq >> 1) ^ (px & 15);
            bf16x4 st;
            st[0] = (__bf16)r0[r2]; st[1] = (__bf16)r1[r2];
            st[2] = (__bf16)r2_[r2]; st[3] = (__bf16)r3[r2];
            *(bf16x4*)&xt[px * 128 + blki * 8 + (icq & 1) * 4] = st;
        }
    }
    __syncthreads();

    int lane = tid & 63, wv = tid >> 6;
    int p = lane & 15, q = lane >> 4;

    f32x4 acc[4];
#pragma unroll
    for (int n = 0; n < 4; ++n) acc[n] = (f32x4){0.f, 0.f, 0.f, 0.f};

#pragma unroll
    for (int kk = 0; kk < 4; ++kk) {
        int blki = (kk * 4 + q) ^ p;
        bf16x8 a = *(const bf16x8*)&xt[(wv * 16 + p) * 128 + blki * 8];
#pragma unroll
        for (int n = 0; n < 4; ++n) {
            bf16x8 bb = *(const bf16x8*)&wt[(n * 16 + p) * 128 + blki * 8];
            acc[n] = __builtin_amdgcn_mfma_f32_16x16x32_bf16(a, bb, acc[n], 0, 0, 0);
        }
    }

    // D: col(oc within tile) = p, row(px within tile) = q*4+rg
    __bf16* t1b = t1c + ((size_t)b * HW_ + px0 + wv * 16) * 64;
#pragma unroll
    for (int n = 0; n < 4; ++n) {
        float s = 0.f, qq = 0.f;
#pragma unroll
        for (int rg = 0; rg < 4; ++rg) {
            float v = acc[n][rg];
            t1b[(size_t)(q * 4 + rg) * 64 + n * 16 + p] = (__bf16)v;
            s += v; qq += v * v;
        }
        s += __shfl_down(s, 32, 64);  s += __shfl_down(s, 16, 64);
        qq += __shfl_down(qq, 32, 64); qq += __shfl_down(qq, 16, 64);
        if (lane < 16) {
            atomicAdd(&sS[n * 16 + p], s);
            atomicAdd(&sQ[n * 16 + p], qq);
        }
    }
    __syncthreads();
    if (tid < 64) {
        atomicAdd(&csum[tid], sS[tid]);
        atomicAdd(&csq[tid], sQ[tid]);
    }
}

// ---------------- K2: 3x3 conv MFMA; B-operand through double-buffered LDS ----------------
// grid 512 = b(8) x tile(64 of 8x8 px); 256 thr = 4 waves.
__global__ __launch_bounds__(256, 4) void k_conv3(const __bf16* __restrict__ t1c,
                                                  const __bf16* __restrict__ wprep,
                                                  const float* __restrict__ csum,
                                                  const float* __restrict__ csq,
                                                  const float* __restrict__ cg,
                                                  const float* __restrict__ cb,
                                                  float* __restrict__ t2c,
                                                  float* __restrict__ esum,
                                                  float* __restrict__ esq) {
    __shared__ __bf16 xt[10 * 10 * 72];        // 14400 B
    __shared__ __bf16 bt[2][112 * 32];         // [buf][oc][32k] = 2 x 7168 B
    __shared__ float lsc[64], lsh[64];
    __shared__ float esuml[112], esql[112];

    int blk = blockIdx.x;
    int b = blk & 7;
    int tile = blk >> 3;
    int ty0 = (tile >> 3) * 8, tx0 = (tile & 7) * 8;
    int tid = threadIdx.x;
    if (tid < 112) { esuml[tid] = 0.f; esql[tid] = 0.f; }
    if (tid >= 128 && tid < 192) {
        int c = tid - 128;
        float invN = 1.0f / NSTAT_;
        float m = csum[c] * invN;
        float v = csq[c] * invN - m * m;
        float rs = rsqrtf(v + 1e-5f);
        float sc = cg[c] * rs;
        lsc[c] = sc;
        lsh[c] = cb[c] - m * sc;
    }
    __syncthreads();   // lsc/lsh ready for staging

    // prologue: stage B chunk kk=0 into bt[0]  (448 chunks of 16B)
    {
        int oc = tid >> 2, part = tid & 3;
        *(bf16x8*)&bt[0][oc * 32 + part * 8] =
            *(const bf16x8*)(wprep + (size_t)oc * 576 + part * 8);
        if (tid < 192) {
            int c1 = tid + 256;
            int oc1 = c1 >> 2, p1 = c1 & 3;
            *(bf16x8*)&bt[0][oc1 * 32 + p1 * 8] =
                *(const bf16x8*)(wprep + (size_t)oc1 * 576 + p1 * 8);
        }
    }

    // stage BN+SiLU(t1) 10x10 halo -> xt  (1600 jobs of 4 ic)
    const __bf16* tb = t1c + (size_t)b * HW_ * 64;
#pragma unroll
    for (int it = 0; it < 7; ++it) {
        int idx = it * 256 + tid;
        if (idx < 1600) {
            int pxi = idx >> 4, f4 = idx & 15;
            int yy = pxi / 10, xx = pxi - yy * 10;
            int gy = ty0 + yy - 1, gx = tx0 + xx - 1;
            float o0 = 0.f, o1 = 0.f, o2 = 0.f, o3 = 0.f;
            if (gy >= 0 && gy < 64 && gx >= 0 && gx < 64) {
                bf16x4 v = *(const bf16x4*)(tb + ((size_t)(gy << 6) + gx) * 64 + f4 * 4);
                float4 sc = *(const float4*)(lsc + f4 * 4);
                float4 sh = *(const float4*)(lsh + f4 * 4);
                float u;
                u = fmaf((float)v[0], sc.x, sh.x); o0 = u / (1.f + __expf(-u));
                u = fmaf((float)v[1], sc.y, sh.y); o1 = u / (1.f + __expf(-u));
                u = fmaf((float)v[2], sc.z, sh.z); o2 = u / (1.f + __expf(-u));
                u = fmaf((float)v[3], sc.w, sh.w); o3 = u / (1.f + __expf(-u));
            }
            bf16x4 st;
            st[0] = (__bf16)o0; st[1] = (__bf16)o1; st[2] = (__bf16)o2; st[3] = (__bf16)o3;
            *(bf16x4*)&xt[pxi * 72 + f4 * 4] = st;
        }
    }
    __syncthreads();   // bt[0] + xt ready

    int lane = tid & 63, wv = tid >> 6;
    int p = lane & 15, q = lane >> 4;
    int ya = 2 * wv + (p >> 3), xa = p & 7;
    int soc = tid >> 2, spart = tid & 3;          // staging roles
    int soc1 = (tid + 256) >> 2, spart1 = (tid + 256) & 3;

    f32x4 acc[7];
#pragma unroll
    for (int n = 0; n < 7; ++n) acc[n] = (f32x4){0.f, 0.f, 0.f, 0.f};

#pragma unroll
    for (int kk = 0; kk < 18; ++kk) {
        const int cur = kk & 1;
        // prefetch B chunk kk+1 into regs (coalesced 16B loads, latency overlapped)
        bf16x8 r0, r1;
        if (kk < 17) {
            r0 = *(const bf16x8*)(wprep + (size_t)soc * 576 + (kk + 1) * 32 + spart * 8);
            if (tid < 192)
                r1 = *(const bf16x8*)(wprep + (size_t)soc1 * 576 + (kk + 1) * 32 + spart1 * 8);
        }
        // compute from bt[cur]
        const int tap = kk >> 1, ich = (kk & 1) * 32;
        const int ky = tap / 3, kx = tap - ky * 3;
        bf16x8 a0 = *(const bf16x8*)&xt[((ya + ky) * 10 + xa + kx) * 72 + ich + q * 8];
#pragma unroll
        for (int n = 0; n < 7; ++n) {
            bf16x8 bb = *(const bf16x8*)&bt[cur][(n * 16 + p) * 32 + q * 8];
            acc[n] = __builtin_amdgcn_mfma_f32_16x16x32_bf16(a0, bb, acc[n], 0, 0, 0);
        }
        // write prefetched chunk to the other buffer
        if (kk < 17) {
            *(bf16x8*)&bt[1 - cur][soc * 32 + spart * 8] = r0;
            if (tid < 192)
                *(bf16x8*)&bt[1 - cur][soc1 * 32 + spart1 * 8] = r1;
            __syncthreads();
        }
    }

    float* t2b = t2c + (size_t)b * HW_ * 112;
#pragma unroll
    for (int n = 0; n < 7; ++n) {
        float s = 0.f, qq = 0.f;
#pragma unroll
        for (int rg = 0; rg < 4; ++rg) {
            int mp = q * 4 + rg;
            int y = ty0 + 2 * wv + (mp >> 3), xo = tx0 + (mp & 7);
            float v = acc[n][rg];
            t2b[((size_t)y * 64 + xo) * 112 + n * 16 + p] = v;
            s += v; qq += v * v;
        }
        s += __shfl_down(s, 32, 64);  s += __shfl_down(s, 16, 64);
        qq += __shfl_down(qq, 32, 64); qq += __shfl_down(qq, 16, 64);
        if (lane < 16) {
            atomicAdd(&esuml[n * 16 + lane], s);
            atomicAdd(&esql[n * 16 + lane], qq);
        }
    }
    __syncthreads();
    if (tid < 112) {
        atomicAdd(&esum[tid], esuml[tid]);
        atomicAdd(&esq[tid], esql[tid]);
    }
}

// ---------------- K3: BN2 + softmax + reassembly; subpixel-PAIR per thread ----------------
// Round-1 body (proven 128 VGPR, zero spill at launch_bounds(256,2)) with channel QUARTERS:
// grid 1024 = b(8) x tile(32: 4tx x 8ty of 16x8 lowres) x cq(4) -> 4 blocks/CU (grid was the
// occupancy limiter at 512). LDS 39,424 B x 4 = 157.7 KB <= 160 KB. Do NOT force waves=4 in
// launch_bounds: round 2 proved that caps VGPR at 128 -> wholesale array spill (VGPR 64,
// +700 MB scratch HBM traffic). (256,2) lets the allocator land at 128 naturally.
__global__ __launch_bounds__(256, 2) void k_carafe(const float* __restrict__ x,
                                                   const float* __restrict__ t2c,
                                                   const float* __restrict__ esum,
                                                   const float* __restrict__ esq,
                                                   const float* __restrict__ eg,
                                                   const float* __restrict__ eb,
                                                   float* __restrict__ out) {
    __shared__ float xt[2][240 * 20];  // [buf][halo px 12x20][16 ch pad 20] = 2 x 19200 B
    __shared__ float esc[112], esh[112];

    int blk = blockIdx.x;
    int b = blk & 7;
    int r = blk >> 3;                  // 0..127
    int tile = r & 31;
    int cq = r >> 5;                   // 0..3 channel quarter (32 ch = 2 stages of 16)
    int tx0 = (tile & 3) * 16, ty0 = (tile >> 2) * 8;
    int tid = threadIdx.x;
    if (tid < 112) {
        float invN = 1.0f / NSTAT_;
        float m = esum[tid] * invN;
        float v = esq[tid] * invN - m * m;
        float rs = rsqrtf(v + 1e-5f);
        float sc = (tid < OC_) ? eg[tid] * rs : 0.f;
        esc[tid] = sc;
        esh[tid] = (tid < OC_) ? eb[tid] - m * sc : 0.f;
    }
    __syncthreads();

    int t0 = tid & 1, px = tid >> 1;      // t0 = si (output row within 2x2)
    int pxx = px & 15, py = px >> 4;      // py 0..7
    int iy = ty0 + py, jx = tx0 + pxx;

    // two softmaxes: s = 2*t0 (sj=0) and s = 2*t0+1 (sj=1); weight channel = 4k+s
    float wA[25], wB[25];
    {
        const float* t2p = t2c + ((size_t)((b << 12) + (iy << 6) + jx)) * 112 + 2 * t0;
        int cA = 2 * t0, cB = 2 * t0 + 1;
        float mxA = -1e30f, mxB = -1e30f;
#pragma unroll
        for (int k = 0; k < 25; ++k) {
            float2 v = *(const float2*)(t2p + 4 * k);
            float lA = fmaf(v.x, esc[4 * k + cA], esh[4 * k + cA]);
            float lB = fmaf(v.y, esc[4 * k + cB], esh[4 * k + cB]);
            wA[k] = lA; wB[k] = lB;
            mxA = fmaxf(mxA, lA); mxB = fmaxf(mxB, lB);
        }
        float sA = 0.f, sB = 0.f;
#pragma unroll
        for (int k = 0; k < 25; ++k) {
            float eA = __expf(wA[k] - mxA);
            float eB = __expf(wB[k] - mxB);
            wA[k] = eA; wB[k] = eB;
            sA += eA; sB += eB;
        }
        float iA = 1.f / sA, iB = 1.f / sB;
#pragma unroll
        for (int k = 0; k < 25; ++k) { wA[k] *= iA; wB[k] *= iB; }
    }

    const float* xb = x + (size_t)b * C_ * HW_;
    int i0 = iy * 2 + t0;
    float* op = out + (size_t)b * C_ * 16384 + (size_t)i0 * 128 + jx * 2;

    // staging roles (prologue + prefetch): 960 jobs (12x20 halo x 4 c-quads), 4 rounds
    int sidx[4], sgy[4], sgx[4], sr2[4], sc4[4];
#pragma unroll
    for (int it = 0; it < 4; ++it) {
        int idx = it * 256 + tid;
        sidx[it] = idx;
        int c4 = idx / 240;
        int r2 = idx - c4 * 240;
        int yy = r2 / 20, xx = r2 - yy * 20;
        sr2[it] = r2;
        sc4[it] = c4;
        sgy[it] = ty0 - 2 + yy;
        sgx[it] = tx0 - 2 + xx;
    }

    // prologue: stage channels [cq*32, cq*32+16) into xt[0]
#pragma unroll
    for (int it = 0; it < 4; ++it) {
        if (sidx[it] < 960) {
            int gy = sgy[it], gx = sgx[it];
            f32x4 st = {0.f, 0.f, 0.f, 0.f};
            if (gy >= 0 && gy < 64 && gx >= 0 && gx < 64) {
                size_t base = (size_t)(cq * 32 + sc4[it] * 4) * HW_ + (gy << 6) + gx;
                st[0] = xb[base];
                st[1] = xb[base + HW_];
                st[2] = xb[base + 2 * HW_];
                st[3] = xb[base + 3 * HW_];
            }
            *(f32x4*)&xt[0][sr2[it] * 20 + sc4[it] * 4] = st;
        }
    }

#pragma unroll 1
    for (int stage = 0; stage < 2; ++stage) {
        int cur = stage & 1;
        int cbase = cq * 32 + stage * 16;
        // prefetch next stage's 16 channels into regs
        f32x4 pf[4];
        if (stage < 1) {
#pragma unroll
            for (int it = 0; it < 4; ++it) {
                if (sidx[it] < 960) {
                    int gy = sgy[it], gx = sgx[it];
                    f32x4 st = {0.f, 0.f, 0.f, 0.f};
                    if (gy >= 0 && gy < 64 && gx >= 0 && gx < 64) {
                        size_t base = (size_t)(cbase + 16 + sc4[it] * 4) * HW_ + (gy << 6) + gx;
                        st[0] = xb[base];
                        st[1] = xb[base + HW_];
                        st[2] = xb[base + 2 * HW_];
                        st[3] = xb[base + 3 * HW_];
                    }
                    pf[it] = st;
                }
            }
        }
        __syncthreads();   // xt[cur] ready

        float accA[16], accB[16];
#pragma unroll
        for (int e = 0; e < 16; ++e) { accA[e] = 0.f; accB[e] = 0.f; }
#pragma unroll
        for (int dy = 0; dy < 5; ++dy)
#pragma unroll
            for (int dx = 0; dx < 5; ++dx) {
                int pos = (py + dy) * 20 + pxx + dx;
                float a = wA[dy * 5 + dx], bw = wB[dy * 5 + dx];
#pragma unroll
                for (int c4 = 0; c4 < 4; ++c4) {
                    f32x4 xv = *(const f32x4*)&xt[cur][pos * 20 + c4 * 4];
                    accA[c4 * 4 + 0] = fmaf(a, xv[0], accA[c4 * 4 + 0]);
                    accA[c4 * 4 + 1] = fmaf(a, xv[1], accA[c4 * 4 + 1]);
                    accA[c4 * 4 + 2] = fmaf(a, xv[2], accA[c4 * 4 + 2]);
                    accA[c4 * 4 + 3] = fmaf(a, xv[3], accA[c4 * 4 + 3]);
                    accB[c4 * 4 + 0] = fmaf(bw, xv[0], accB[c4 * 4 + 0]);
                    accB[c4 * 4 + 1] = fmaf(bw, xv[1], accB[c4 * 4 + 1]);
                    accB[c4 * 4 + 2] = fmaf(bw, xv[2], accB[c4 * 4 + 2]);
                    accB[c4 * 4 + 3] = fmaf(bw, xv[3], accB[c4 * 4 + 3]);
                }
            }
        // paired subpixels are adjacent output columns -> 8B vector stores
#pragma unroll
        for (int e = 0; e < 16; ++e) {
            float2 st2;
            st2.x = accA[e]; st2.y = accB[e];
            *(float2*)&op[(size_t)(cbase + e) * 16384] = st2;
        }

        if (stage < 1) {
#pragma unroll
            for (int it = 0; it < 4; ++it) {
                if (sidx[it] < 960)
                    *(f32x4*)&xt[1 - cur][sr2[it] * 20 + sc4[it] * 4] = pf[it];
            }
        }
    }
}

extern "C" void kernel_launch(void* const* d_in, const int* in_sizes, int n_in,
                              void* d_out, int out_size, void* d_ws, size_t ws_size,
                              hipStream_t stream) {
    const float* x      = (const float*)d_in[0];
    const float* comp_w = (const float*)d_in[1];
    const float* comp_g = (const float*)d_in[2];
    const float* comp_b = (const float*)d_in[3];
    const float* enc_w  = (const float*)d_in[4];
    const float* enc_g  = (const float*)d_in[5];
    const float* enc_b  = (const float*)d_in[6];
    float* out = (float*)d_out;

    float* ws = (float*)d_ws;
    __bf16* t1c = (__bf16*)ws;             // 8*4096*64 bf16 = 4 MB
    float* t2c  = ws + 1048576;            // 8*4096*112 fp32 = 14.7 MB
    float* st   = ws + 1048576 + 3670016;
    float* csum = st;                      // 64
    float* csq  = st + 64;                 // 64
    float* esum = st + 128;                // 112
    float* esq  = st + 240;                // 112
    __bf16* wprep = (__bf16*)(st + 352);   // 112*576 bf16

    hipMemsetAsync(st, 0, 352 * sizeof(float), stream);
    k_conv1<<<512, 256, 0, stream>>>(x, comp_w, enc_w, t1c, csum, csq, wprep);
    k_conv3<<<512, 256, 0, stream>>>(t1c, wprep, csum, csq, comp_g, comp_b, t2c, esum, esq);
    k_carafe<<<1024, 256, 0, stream>>>(x, t2c, esum, esq, enc_g, enc_b, out);
}

// Round 4
// 158.687 us; speedup vs baseline: 2.1247x; 1.1130x over previous
//
#include <hip/hip_runtime.h>
#include <hip/hip_bf16.h>
#include <math.h>

#define C_   128
#define HW_  4096
#define OC_  100
#define NSTAT_ 32768.0f

typedef __bf16 bf16x8 __attribute__((ext_vector_type(8)));
typedef __bf16 bf16x4 __attribute__((ext_vector_type(4)));
typedef float  f32x4  __attribute__((ext_vector_type(4)));

// ---------------- K1: 1x1 conv via MFMA bf16 -> t1c[b][px][64] bf16 + stats + wprep --------
// grid 512 = b(8) x chunk(64 of 64px); 256 thr = 4 waves, wave = one 16-px m-tile, N=64.
__global__ __launch_bounds__(256, 4) void k_conv1(const float* __restrict__ x,
                                                  const float* __restrict__ w,
                                                  const float* __restrict__ wenc,
                                                  __bf16* __restrict__ t1c,
                                                  float* __restrict__ csum,
                                                  float* __restrict__ csq,
                                                  __bf16* __restrict__ wprep) {
    __shared__ __bf16 xt[64 * 128];   // [px][ic], 256B rows, 16B-block XOR swizzle
    __shared__ __bf16 wt[64 * 128];   // [oc][ic], same swizzle
    __shared__ float sS[64], sQ[64];

    int blk = blockIdx.x;
    int b = blk & 7;
    int chunk = blk >> 3;             // 0..63
    int px0 = chunk * 64;
    int tid = threadIdx.x;
    if (tid < 64) { sS[tid] = 0.f; sQ[tid] = 0.f; }

    // pack enc weights -> wprep[oc 112][k 576], k = tap*64+ic  (blocks 0..62, 1024 each)
    if (blk < 63) {
#pragma unroll
        for (int u = 0; u < 4; ++u) {
            int idx = blk * 1024 + u * 256 + tid;   // < 64512 = 112*576
            int oc = idx / 576, k = idx - oc * 576;
            int tap = k >> 6, ic = k & 63;
            wprep[idx] = (oc < OC_) ? (__bf16)wenc[((size_t)oc * 64 + ic) * 9 + tap]
                                    : (__bf16)0.f;
        }
    }

    // stage comp_w (64 oc x 128 ic fp32) -> wt bf16: 2048 float4 jobs
#pragma unroll
    for (int it = 0; it < 8; ++it) {
        int j = it * 256 + tid;       // 0..2047
        int oc = j >> 5, f = j & 31;
        float4 v = *(const float4*)(w + (size_t)oc * 128 + f * 4);
        int blki = (f >> 1) ^ (oc & 15);
        bf16x4 st;
        st[0] = (__bf16)v.x; st[1] = (__bf16)v.y; st[2] = (__bf16)v.z; st[3] = (__bf16)v.w;
        *(bf16x4*)&wt[oc * 128 + blki * 8 + (f & 1) * 4] = st;
    }
    // stage x tile (64 px x 128 ic) -> xt bf16 (transpose 4x4 in regs), 512 jobs x 16 floats
#pragma unroll
    for (int it = 0; it < 2; ++it) {
        int j = it * 256 + tid;
        int px4 = (j & 15) * 4, icq = j >> 4;   // icq 0..31
        const float* xp = x + ((size_t)b * C_ + icq * 4) * HW_ + px0 + px4;
        float4 v0 = *(const float4*)(xp);
        float4 v1 = *(const float4*)(xp + HW_);
        float4 v2 = *(const float4*)(xp + 2 * HW_);
        float4 v3 = *(const float4*)(xp + 3 * HW_);
        float r0[4] = {v0.x, v0.y, v0.z, v0.w};
        float r1[4] = {v1.x, v1.y, v1.z, v1.w};
        float r2_[4] = {v2.x, v2.y, v2.z, v2.w};
        float r3[4] = {v3.x, v3.y, v3.z, v3.w};
#pragma unroll
        for (int r2 = 0; r2 < 4; ++r2) {
            int px = px4 + r2;
            int blki = (icq >> 1) ^ (px & 15);
            bf16x4 st;
            st[0] = (__bf16)r0[r2]; st[1] = (__bf16)r1[r2];
            st[2] = (__bf16)r2_[r2]; st[3] = (__bf16)r3[r2];
            *(bf16x4*)&xt[px * 128 + blki * 8 + (icq & 1) * 4] = st;
        }
    }
    __syncthreads();

    int lane = tid & 63, wv = tid >> 6;
    int p = lane & 15, q = lane >> 4;

    f32x4 acc[4];
#pragma unroll
    for (int n = 0; n < 4; ++n) acc[n] = (f32x4){0.f, 0.f, 0.f, 0.f};

#pragma unroll
    for (int kk = 0; kk < 4; ++kk) {
        int blki = (kk * 4 + q) ^ p;
        bf16x8 a = *(const bf16x8*)&xt[(wv * 16 + p) * 128 + blki * 8];
#pragma unroll
        for (int n = 0; n < 4; ++n) {
            bf16x8 bb = *(const bf16x8*)&wt[(n * 16 + p) * 128 + blki * 8];
            acc[n] = __builtin_amdgcn_mfma_f32_16x16x32_bf16(a, bb, acc[n], 0, 0, 0);
        }
    }

    // D: col(oc within tile) = p, row(px within tile) = q*4+rg
    __bf16* t1b = t1c + ((size_t)b * HW_ + px0 + wv * 16) * 64;
#pragma unroll
    for (int n = 0; n < 4; ++n) {
        float s = 0.f, qq = 0.f;
#pragma unroll
        for (int rg = 0; rg < 4; ++rg) {
            float v = acc[n][rg];
            t1b[(size_t)(q * 4 + rg) * 64 + n * 16 + p] = (__bf16)v;
            s += v; qq += v * v;
        }
        s += __shfl_down(s, 32, 64);  s += __shfl_down(s, 16, 64);
        qq += __shfl_down(qq, 32, 64); qq += __shfl_down(qq, 16, 64);
        if (lane < 16) {
            atomicAdd(&sS[n * 16 + p], s);
            atomicAdd(&sQ[n * 16 + p], qq);
        }
    }
    __syncthreads();
    if (tid < 64) {
        atomicAdd(&csum[tid], sS[tid]);
        atomicAdd(&csq[tid], sQ[tid]);
    }
}

// ---------------- K2: 3x3 conv MFMA; B-operand through double-buffered LDS ----------------
// grid 512 = b(8) x tile(64 of 8x8 px); 256 thr = 4 waves.
// t2c now written TRANSPOSED: [b][k=25][pxl=4096][s=4] (oc = 4k+s, oc<100) so that
// k_carafe's per-pixel softmax reads are coalesced float2 loads instead of 448B-stride
// scatter. Block writes full 128B row segments per k-plane -> no write amplification.
__global__ __launch_bounds__(256, 4) void k_conv3(const __bf16* __restrict__ t1c,
                                                  const __bf16* __restrict__ wprep,
                                                  const float* __restrict__ csum,
                                                  const float* __restrict__ csq,
                                                  const float* __restrict__ cg,
                                                  const float* __restrict__ cb,
                                                  float* __restrict__ t2c,
                                                  float* __restrict__ esum,
                                                  float* __restrict__ esq) {
    __shared__ __bf16 xt[10 * 10 * 72];        // 14400 B
    __shared__ __bf16 bt[2][112 * 32];         // [buf][oc][32k] = 2 x 7168 B
    __shared__ float lsc[64], lsh[64];
    __shared__ float esuml[112], esql[112];

    int blk = blockIdx.x;
    int b = blk & 7;
    int tile = blk >> 3;
    int ty0 = (tile >> 3) * 8, tx0 = (tile & 7) * 8;
    int tid = threadIdx.x;
    if (tid < 112) { esuml[tid] = 0.f; esql[tid] = 0.f; }
    if (tid >= 128 && tid < 192) {
        int c = tid - 128;
        float invN = 1.0f / NSTAT_;
        float m = csum[c] * invN;
        float v = csq[c] * invN - m * m;
        float rs = rsqrtf(v + 1e-5f);
        float sc = cg[c] * rs;
        lsc[c] = sc;
        lsh[c] = cb[c] - m * sc;
    }
    __syncthreads();   // lsc/lsh ready for staging

    // prologue: stage B chunk kk=0 into bt[0]  (448 chunks of 16B)
    {
        int oc = tid >> 2, part = tid & 3;
        *(bf16x8*)&bt[0][oc * 32 + part * 8] =
            *(const bf16x8*)(wprep + (size_t)oc * 576 + part * 8);
        if (tid < 192) {
            int c1 = tid + 256;
            int oc1 = c1 >> 2, p1 = c1 & 3;
            *(bf16x8*)&bt[0][oc1 * 32 + p1 * 8] =
                *(const bf16x8*)(wprep + (size_t)oc1 * 576 + p1 * 8);
        }
    }

    // stage BN+SiLU(t1) 10x10 halo -> xt  (1600 jobs of 4 ic)
    const __bf16* tb = t1c + (size_t)b * HW_ * 64;
#pragma unroll
    for (int it = 0; it < 7; ++it) {
        int idx = it * 256 + tid;
        if (idx < 1600) {
            int pxi = idx >> 4, f4 = idx & 15;
            int yy = pxi / 10, xx = pxi - yy * 10;
            int gy = ty0 + yy - 1, gx = tx0 + xx - 1;
            float o0 = 0.f, o1 = 0.f, o2 = 0.f, o3 = 0.f;
            if (gy >= 0 && gy < 64 && gx >= 0 && gx < 64) {
                bf16x4 v = *(const bf16x4*)(tb + ((size_t)(gy << 6) + gx) * 64 + f4 * 4);
                float4 sc = *(const float4*)(lsc + f4 * 4);
                float4 sh = *(const float4*)(lsh + f4 * 4);
                float u;
                u = fmaf((float)v[0], sc.x, sh.x); o0 = u / (1.f + __expf(-u));
                u = fmaf((float)v[1], sc.y, sh.y); o1 = u / (1.f + __expf(-u));
                u = fmaf((float)v[2], sc.z, sh.z); o2 = u / (1.f + __expf(-u));
                u = fmaf((float)v[3], sc.w, sh.w); o3 = u / (1.f + __expf(-u));
            }
            bf16x4 st;
            st[0] = (__bf16)o0; st[1] = (__bf16)o1; st[2] = (__bf16)o2; st[3] = (__bf16)o3;
            *(bf16x4*)&xt[pxi * 72 + f4 * 4] = st;
        }
    }
    __syncthreads();   // bt[0] + xt ready

    int lane = tid & 63, wv = tid >> 6;
    int p = lane & 15, q = lane >> 4;
    int ya = 2 * wv + (p >> 3), xa = p & 7;
    int soc = tid >> 2, spart = tid & 3;          // staging roles
    int soc1 = (tid + 256) >> 2, spart1 = (tid + 256) & 3;

    f32x4 acc[7];
#pragma unroll
    for (int n = 0; n < 7; ++n) acc[n] = (f32x4){0.f, 0.f, 0.f, 0.f};

#pragma unroll
    for (int kk = 0; kk < 18; ++kk) {
        const int cur = kk & 1;
        // prefetch B chunk kk+1 into regs (coalesced 16B loads, latency overlapped)
        bf16x8 r0, r1;
        if (kk < 17) {
            r0 = *(const bf16x8*)(wprep + (size_t)soc * 576 + (kk + 1) * 32 + spart * 8);
            if (tid < 192)
                r1 = *(const bf16x8*)(wprep + (size_t)soc1 * 576 + (kk + 1) * 32 + spart1 * 8);
        }
        // compute from bt[cur]
        const int tap = kk >> 1, ich = (kk & 1) * 32;
        const int ky = tap / 3, kx = tap - ky * 3;
        bf16x8 a0 = *(const bf16x8*)&xt[((ya + ky) * 10 + xa + kx) * 72 + ich + q * 8];
#pragma unroll
        for (int n = 0; n < 7; ++n) {
            bf16x8 bb = *(const bf16x8*)&bt[cur][(n * 16 + p) * 32 + q * 8];
            acc[n] = __builtin_amdgcn_mfma_f32_16x16x32_bf16(a0, bb, acc[n], 0, 0, 0);
        }
        // write prefetched chunk to the other buffer
        if (kk < 17) {
            *(bf16x8*)&bt[1 - cur][soc * 32 + spart * 8] = r0;
            if (tid < 192)
                *(bf16x8*)&bt[1 - cur][soc1 * 32 + spart1 * 8] = r1;
            __syncthreads();
        }
    }

    // epilogue: write transposed t2c[b][k][pxl][s], oc = 4k+s; stats over all 112 (harmless)
    float* t2b = t2c + (size_t)b * 25 * HW_ * 4;
#pragma unroll
    for (int n = 0; n < 7; ++n) {
        int oc = n * 16 + p;
        int k5 = oc >> 2, sch = oc & 3;
        bool wr = oc < OC_;
        float s = 0.f, qq = 0.f;
#pragma unroll
        for (int rg = 0; rg < 4; ++rg) {
            int mp = q * 4 + rg;
            int y = ty0 + 2 * wv + (mp >> 3), xo = tx0 + (mp & 7);
            float v = acc[n][rg];
            if (wr) t2b[((size_t)k5 * HW_ + (y << 6) + xo) * 4 + sch] = v;
            s += v; qq += v * v;
        }
        s += __shfl_down(s, 32, 64);  s += __shfl_down(s, 16, 64);
        qq += __shfl_down(qq, 32, 64); qq += __shfl_down(qq, 16, 64);
        if (lane < 16) {
            atomicAdd(&esuml[n * 16 + lane], s);
            atomicAdd(&esql[n * 16 + lane], qq);
        }
    }
    __syncthreads();
    if (tid < 112) {
        atomicAdd(&esum[tid], esuml[tid]);
        atomicAdd(&esq[tid], esql[tid]);
    }
}

// ---------------- K3: BN2 + softmax + reassembly; subpixel-PAIR, 512-thread blocks --------
// Rounds 1-3 evidence: only ~2 blocks/CU co-reside regardless of theoretical 4 (suspect
// usable-LDS pool or WG cap). Fix: 8-wave (512-thr) blocks + SINGLE 32KB LDS buffer, so
// 2 co-resident blocks already give 16 waves/CU (the VGPR=128 maximum) -> LDS pipe
// saturates. Stage-to-stage prefetch goes through regs (pf/pg) instead of a 2nd buffer.
// grid 512 = b(8) x tile(16: 4x4 of 16x16 lowres) x cq(4 of 32ch); thread = subpixel pair.
// t2c logits now [b][k][pxl][4]: softmax loads are fully coalesced float2.
__global__ __launch_bounds__(512, 2) void k_carafe(const float* __restrict__ x,
                                                   const float* __restrict__ t2c,
                                                   const float* __restrict__ esum,
                                                   const float* __restrict__ esq,
                                                   const float* __restrict__ eg,
                                                   const float* __restrict__ eb,
                                                   float* __restrict__ out) {
    __shared__ float xt[400 * 20];     // [halo px 20x20][16 ch pad 20] = 32000 B
    __shared__ float esc[112], esh[112];

    int blk = blockIdx.x;
    int b = blk & 7;
    int r = blk >> 3;                  // 0..63
    int tile = r & 15;
    int cq = r >> 4;                   // 0..3 channel quarter (32 ch = 2 stages of 16)
    int tx0 = (tile & 3) * 16, ty0 = (tile >> 2) * 16;
    int tid = threadIdx.x;
    if (tid < 112) {
        float invN = 1.0f / NSTAT_;
        float m = esum[tid] * invN;
        float v = esq[tid] * invN - m * m;
        float rs = rsqrtf(v + 1e-5f);
        float sc = (tid < OC_) ? eg[tid] * rs : 0.f;
        esc[tid] = sc;
        esh[tid] = (tid < OC_) ? eb[tid] - m * sc : 0.f;
    }

    int t0 = tid & 1, px = tid >> 1;      // t0 = si (output row within 2x2), px 0..255
    int pxx = px & 15, py = px >> 4;      // py 0..15
    int iy = ty0 + py, jx = tx0 + pxx;
    int pxl = (iy << 6) + jx;

    const float* xb = x + (size_t)b * C_ * HW_;

    // issue stage-0 x loads into regs now; they complete under the softmax below
    f32x4 pf[4];
#pragma unroll
    for (int it = 0; it < 4; ++it) {
        int idx = it * 512 + tid;          // 1600 jobs = 400 halo px x 4 c-quads
        if (idx < 1600) {
            int c4 = idx / 400;
            int hp = idx - c4 * 400;
            int yy = hp / 20, xx = hp - yy * 20;
            int gy = ty0 - 2 + yy, gx = tx0 - 2 + xx;
            f32x4 st = {0.f, 0.f, 0.f, 0.f};
            if (gy >= 0 && gy < 64 && gx >= 0 && gx < 64) {
                size_t base = (size_t)(cq * 32 + c4 * 4) * HW_ + (gy << 6) + gx;
                st[0] = xb[base];
                st[1] = xb[base + HW_];
                st[2] = xb[base + 2 * HW_];
                st[3] = xb[base + 3 * HW_];
            }
            pf[it] = st;
        }
    }
    __syncthreads();   // esc/esh ready

    // two softmaxes (channels 2*t0, 2*t0+1); coalesced: wave reads 512B per tap plane
    float wA[25], wB[25];
    {
        const float* t2p = t2c + (size_t)b * 25 * HW_ * 4 + (size_t)pxl * 4 + 2 * t0;
        int cA = 2 * t0, cB = 2 * t0 + 1;
        float mxA = -1e30f, mxB = -1e30f;
#pragma unroll
        for (int k = 0; k < 25; ++k) {
            float2 v = *(const float2*)(t2p + (size_t)k * HW_ * 4);
            float lA = fmaf(v.x, esc[4 * k + cA], esh[4 * k + cA]);
            float lB = fmaf(v.y, esc[4 * k + cB], esh[4 * k + cB]);
            wA[k] = lA; wB[k] = lB;
            mxA = fmaxf(mxA, lA); mxB = fmaxf(mxB, lB);
        }
        float sA = 0.f, sB = 0.f;
#pragma unroll
        for (int k = 0; k < 25; ++k) {
            float eA = __expf(wA[k] - mxA);
            float eB = __expf(wB[k] - mxB);
            wA[k] = eA; wB[k] = eB;
            sA += eA; sB += eB;
        }
        float iA = 1.f / sA, iB = 1.f / sB;
#pragma unroll
        for (int k = 0; k < 25; ++k) { wA[k] *= iA; wB[k] *= iB; }
    }

    // stage-0 data -> LDS
#pragma unroll
    for (int it = 0; it < 4; ++it) {
        int idx = it * 512 + tid;
        if (idx < 1600) {
            int c4 = idx / 400;
            int hp = idx - c4 * 400;
            *(f32x4*)&xt[hp * 20 + c4 * 4] = pf[it];
        }
    }
    __syncthreads();   // xt = stage 0

    int i0 = iy * 2 + t0;
    float* op = out + (size_t)b * C_ * 16384 + (size_t)i0 * 128 + jx * 2;
    int cbase = cq * 32;

    // prefetch stage-1 channels into regs (completes under stage-0 compute)
    f32x4 pg[4];
#pragma unroll
    for (int it = 0; it < 4; ++it) {
        int idx = it * 512 + tid;
        if (idx < 1600) {
            int c4 = idx / 400;
            int hp = idx - c4 * 400;
            int yy = hp / 20, xx = hp - yy * 20;
            int gy = ty0 - 2 + yy, gx = tx0 - 2 + xx;
            f32x4 st = {0.f, 0.f, 0.f, 0.f};
            if (gy >= 0 && gy < 64 && gx >= 0 && gx < 64) {
                size_t base = (size_t)(cbase + 16 + c4 * 4) * HW_ + (gy << 6) + gx;
                st[0] = xb[base];
                st[1] = xb[base + HW_];
                st[2] = xb[base + 2 * HW_];
                st[3] = xb[base + 3 * HW_];
            }
            pg[it] = st;
        }
    }

    // ---- stage 0 compute ----
    {
        float accA[16], accB[16];
#pragma unroll
        for (int e = 0; e < 16; ++e) { accA[e] = 0.f; accB[e] = 0.f; }
#pragma unroll
        for (int dy = 0; dy < 5; ++dy)
#pragma unroll
            for (int dx = 0; dx < 5; ++dx) {
                int pos = (py + dy) * 20 + pxx + dx;
                float a = wA[dy * 5 + dx], bw = wB[dy * 5 + dx];
#pragma unroll
                for (int c4 = 0; c4 < 4; ++c4) {
                    f32x4 xv = *(const f32x4*)&xt[pos * 20 + c4 * 4];
                    accA[c4 * 4 + 0] = fmaf(a, xv[0], accA[c4 * 4 + 0]);
                    accA[c4 * 4 + 1] = fmaf(a, xv[1], accA[c4 * 4 + 1]);
                    accA[c4 * 4 + 2] = fmaf(a, xv[2], accA[c4 * 4 + 2]);
                    accA[c4 * 4 + 3] = fmaf(a, xv[3], accA[c4 * 4 + 3]);
                    accB[c4 * 4 + 0] = fmaf(bw, xv[0], accB[c4 * 4 + 0]);
                    accB[c4 * 4 + 1] = fmaf(bw, xv[1], accB[c4 * 4 + 1]);
                    accB[c4 * 4 + 2] = fmaf(bw, xv[2], accB[c4 * 4 + 2]);
                    accB[c4 * 4 + 3] = fmaf(bw, xv[3], accB[c4 * 4 + 3]);
                }
            }
#pragma unroll
        for (int e = 0; e < 16; ++e) {
            float2 st2;
            st2.x = accA[e]; st2.y = accB[e];
            *(float2*)&op[(size_t)(cbase + e) * 16384] = st2;
        }
    }
    __syncthreads();   // all reads of stage 0 done

    // stage-1 data -> LDS
#pragma unroll
    for (int it = 0; it < 4; ++it) {
        int idx = it * 512 + tid;
        if (idx < 1600) {
            int c4 = idx / 400;
            int hp = idx - c4 * 400;
            *(f32x4*)&xt[hp * 20 + c4 * 4] = pg[it];
        }
    }
    __syncthreads();   // xt = stage 1

    // ---- stage 1 compute ----
    {
        float accA[16], accB[16];
#pragma unroll
        for (int e = 0; e < 16; ++e) { accA[e] = 0.f; accB[e] = 0.f; }
#pragma unroll
        for (int dy = 0; dy < 5; ++dy)
#pragma unroll
            for (int dx = 0; dx < 5; ++dx) {
                int pos = (py + dy) * 20 + pxx + dx;
                float a = wA[dy * 5 + dx], bw = wB[dy * 5 + dx];
#pragma unroll
                for (int c4 = 0; c4 < 4; ++c4) {
                    f32x4 xv = *(const f32x4*)&xt[pos * 20 + c4 * 4];
                    accA[c4 * 4 + 0] = fmaf(a, xv[0], accA[c4 * 4 + 0]);
                    accA[c4 * 4 + 1] = fmaf(a, xv[1], accA[c4 * 4 + 1]);
                    accA[c4 * 4 + 2] = fmaf(a, xv[2], accA[c4 * 4 + 2]);
                    accA[c4 * 4 + 3] = fmaf(a, xv[3], accA[c4 * 4 + 3]);
                    accB[c4 * 4 + 0] = fmaf(bw, xv[0], accB[c4 * 4 + 0]);
                    accB[c4 * 4 + 1] = fmaf(bw, xv[1], accB[c4 * 4 + 1]);
                    accB[c4 * 4 + 2] = fmaf(bw, xv[2], accB[c4 * 4 + 2]);
                    accB[c4 * 4 + 3] = fmaf(bw, xv[3], accB[c4 * 4 + 3]);
                }
            }
#pragma unroll
        for (int e = 0; e < 16; ++e) {
            float2 st2;
            st2.x = accA[e]; st2.y = accB[e];
            *(float2*)&op[(size_t)(cbase + 16 + e) * 16384] = st2;
        }
    }
}

extern "C" void kernel_launch(void* const* d_in, const int* in_sizes, int n_in,
                              void* d_out, int out_size, void* d_ws, size_t ws_size,
                              hipStream_t stream) {
    const float* x      = (const float*)d_in[0];
    const float* comp_w = (const float*)d_in[1];
    const float* comp_g = (const float*)d_in[2];
    const float* comp_b = (const float*)d_in[3];
    const float* enc_w  = (const float*)d_in[4];
    const float* enc_g  = (const float*)d_in[5];
    const float* enc_b  = (const float*)d_in[6];
    float* out = (float*)d_out;

    float* ws = (float*)d_ws;
    __bf16* t1c = (__bf16*)ws;             // 8*4096*64 bf16 = 4 MB
    float* t2c  = ws + 1048576;            // 8*25*4096*4 fp32 = 13.1 MB (transposed layout)
    float* st   = ws + 1048576 + 3670016;
    float* csum = st;                      // 64
    float* csq  = st + 64;                 // 64
    float* esum = st + 128;                // 112
    float* esq  = st + 240;                // 112
    __bf16* wprep = (__bf16*)(st + 352);   // 112*576 bf16

    hipMemsetAsync(st, 0, 352 * sizeof(float), stream);
    k_conv1<<<512, 256, 0, stream>>>(x, comp_w, enc_w, t1c, csum, csq, wprep);
    k_conv3<<<512, 256, 0, stream>>>(t1c, wprep, csum, csq, comp_g, comp_b, t2c, esum, esq);
    k_carafe<<<512, 512, 0, stream>>>(x, t2c, esum, esq, enc_g, enc_b, out);
}